// Round 2
// baseline (131.901 us; speedup 1.0000x reference)
//
#include <hip/hip_runtime.h>

#define NQ 32768
#define NC 8192
#define CFEAT 128
#define CSPLIT 4
#define TILE (NC / CSPLIT)   // 2048 coords per split
#define BLK 256

// Phase 1: per-split partial argmin. Each thread owns one query point and
// scans TILE coords staged in LDS.
//
// Numerics (must be BIT-EXACT vs the harness reference): the reference
// computes dists = cc - 2.0 * einsum("md,nd->mn", points, coords). The
// einsum lowers to a GEMM whose K=3 inner loop is an ascending FMA chain
// with acc=0:  dot = fma(pz,cz, fma(py,cy, round(px*cx))).
// Then dists = round(cc - 2*dot)  (the 2.0* is a power-of-2 scale: exact).
// We pre-fold -2 into the staged coords: scaling by -2 is exact and
// commutes with round-to-nearest through fmul and fma, so
//   t0 = (-2cx)*px; t1 = fma(-2cy,py,t0); t2 = fma(-2cz,pz,t1); d = cc + t2
// is bitwise equal to cc - 2*fma_chain_dot.
__global__ __launch_bounds__(BLK) void argmin_part(
    const float* __restrict__ coords, const float* __restrict__ points,
    float* __restrict__ bestd, int* __restrict__ besti) {
  __shared__ float4 sc[TILE];
  const int q = blockIdx.x * BLK + threadIdx.x;
  const int s = blockIdx.y;
  const int base = s * TILE;

  // Stage this split's coords into LDS, precomputing (-2c, cc).
  // cc rounding order matches np.sum(coords*coords, -1): ((x*x+y*y)+z*z).
  for (int i = threadIdx.x; i < TILE; i += BLK) {
    const float cx = coords[(base + i) * 3 + 0];
    const float cy = coords[(base + i) * 3 + 1];
    const float cz = coords[(base + i) * 3 + 2];
    const float cc = __fadd_rn(
        __fadd_rn(__fmul_rn(cx, cx), __fmul_rn(cy, cy)), __fmul_rn(cz, cz));
    sc[i] = make_float4(-2.0f * cx, -2.0f * cy, -2.0f * cz, cc);
  }
  __syncthreads();

  const float px = points[q * 3 + 0];
  const float py = points[q * 3 + 1];
  const float pz = points[q * 3 + 2];

  float best = __builtin_inff();
  int bi = base;
  #pragma unroll 8
  for (int i = 0; i < TILE; ++i) {
    const float4 c = sc[i];  // all 64 lanes read same addr -> LDS broadcast
    const float t0 = __fmul_rn(c.x, px);
    const float t1 = __fmaf_rn(c.y, py, t0);
    const float t2 = __fmaf_rn(c.z, pz, t1);
    const float d  = __fadd_rn(c.w, t2);
    const bool lt = d < best;              // strict < : first-index tiebreak
    best = lt ? d : best;
    bi   = lt ? (base + i) : bi;
  }
  bestd[s * NQ + q] = best;
  besti[s * NQ + q] = bi;
}

// Phase 2: reduce the CSPLIT partial candidates per query (ascending split
// order + strict < keeps the lowest index on exact ties), then gather the
// 128-float feature row. 32 threads per query row, float4 each.
__global__ __launch_bounds__(256) void reduce_gather(
    const float* __restrict__ feature, const float* __restrict__ bestd,
    const int* __restrict__ besti, float4* __restrict__ out) {
  const int t = blockIdx.x * 256 + threadIdx.x;
  const int q = t >> 5;
  const int j = t & 31;

  float bd = bestd[q];
  int bi = besti[q];
  #pragma unroll
  for (int s = 1; s < CSPLIT; ++s) {
    const float d = bestd[s * NQ + q];
    const int i2 = besti[s * NQ + q];
    if (d < bd) { bd = d; bi = i2; }
  }
  const float4* frow = (const float4*)(feature + (size_t)bi * CFEAT);
  out[(size_t)q * (CFEAT / 4) + j] = frow[j];
}

extern "C" void kernel_launch(void* const* d_in, const int* in_sizes, int n_in,
                              void* d_out, int out_size, void* d_ws, size_t ws_size,
                              hipStream_t stream) {
  const float* coords  = (const float*)d_in[0];   // [8192, 3]
  const float* feature = (const float*)d_in[1];   // [8192, 128]
  const float* points  = (const float*)d_in[2];   // [32768, 3]
  float* out = (float*)d_out;                     // [32768, 128]

  float* bestd = (float*)d_ws;                    // [CSPLIT * NQ]
  int*   besti = (int*)((char*)d_ws + (size_t)CSPLIT * NQ * sizeof(float));

  dim3 grid1(NQ / BLK, CSPLIT);
  argmin_part<<<grid1, BLK, 0, stream>>>(coords, points, bestd, besti);

  const int total = NQ * (CFEAT / 4);             // one thread per float4
  reduce_gather<<<total / 256, 256, 0, stream>>>(feature, bestd, besti,
                                                 (float4*)out);
}

// Round 3
// 119.285 us; speedup vs baseline: 1.1058x; 1.1058x over previous
//
#include <hip/hip_runtime.h>

#define NQ 32768
#define NC 8192
#define CFEAT 128
#define CSPLIT 16
#define TILE (NC / CSPLIT)   // 512 coords per split
#define BLK 256
#define QPT 2                // queries per thread
#define QPB (BLK * QPT)      // 512 queries per block

// Phase 1: per-split partial argmin. Each thread owns TWO query points and
// scans TILE coords staged in LDS (one broadcast ds_read_b128 feeds both
// query chains -> halves LDS-pipe traffic, doubles ILP).
//
// Numerics (BIT-EXACT vs harness reference, verified absmax=0.0 in R1):
// reference computes dists = cc - 2.0 * dot(p, c) where the K=3 dot is an
// ascending FMA chain with acc=0. We pre-fold -2 (power-of-2 scale: exact,
// commutes with round-to-nearest through fmul/fma):
//   t = (-2cx)*px; t = fma(-2cy,py,t); t = fma(-2cz,pz,t); d = cc + t
// Strict < with ascending scan order = lowest-index tiebreak, matching argmin.
__global__ __launch_bounds__(BLK) void argmin_part(
    const float* __restrict__ coords, const float* __restrict__ points,
    float* __restrict__ bestd, int* __restrict__ besti) {
  __shared__ float4 sc[TILE];
  const int s = blockIdx.y;
  const int base = s * TILE;
  const int q0 = blockIdx.x * QPB + threadIdx.x;
  const int q1 = q0 + BLK;

  // Stage this split's coords into LDS, precomputing (-2c, cc).
  // cc rounding order matches np.sum(coords*coords, -1): ((x*x+y*y)+z*z).
  for (int i = threadIdx.x; i < TILE; i += BLK) {
    const float cx = coords[(base + i) * 3 + 0];
    const float cy = coords[(base + i) * 3 + 1];
    const float cz = coords[(base + i) * 3 + 2];
    const float cc = __fadd_rn(
        __fadd_rn(__fmul_rn(cx, cx), __fmul_rn(cy, cy)), __fmul_rn(cz, cz));
    sc[i] = make_float4(-2.0f * cx, -2.0f * cy, -2.0f * cz, cc);
  }
  __syncthreads();

  const float px0 = points[q0 * 3 + 0];
  const float py0 = points[q0 * 3 + 1];
  const float pz0 = points[q0 * 3 + 2];
  const float px1 = points[q1 * 3 + 0];
  const float py1 = points[q1 * 3 + 1];
  const float pz1 = points[q1 * 3 + 2];

  float best0 = __builtin_inff(), best1 = __builtin_inff();
  int bi0 = base, bi1 = base;
  #pragma unroll 8
  for (int i = 0; i < TILE; ++i) {
    const float4 c = sc[i];  // wave-uniform addr -> LDS broadcast, no conflicts
    float t0 = __fmul_rn(c.x, px0);
    t0 = __fmaf_rn(c.y, py0, t0);
    t0 = __fmaf_rn(c.z, pz0, t0);
    const float d0 = __fadd_rn(c.w, t0);
    float t1 = __fmul_rn(c.x, px1);
    t1 = __fmaf_rn(c.y, py1, t1);
    t1 = __fmaf_rn(c.z, pz1, t1);
    const float d1 = __fadd_rn(c.w, t1);
    const bool l0 = d0 < best0;            // strict < : first-index tiebreak
    best0 = l0 ? d0 : best0;
    bi0   = l0 ? (base + i) : bi0;
    const bool l1 = d1 < best1;
    best1 = l1 ? d1 : best1;
    bi1   = l1 ? (base + i) : bi1;
  }
  bestd[s * NQ + q0] = best0;
  besti[s * NQ + q0] = bi0;
  bestd[s * NQ + q1] = best1;
  besti[s * NQ + q1] = bi1;
}

// Phase 2: reduce the CSPLIT partial candidates per query (ascending split
// order + strict < keeps the lowest index on exact ties), then gather the
// 128-float feature row. 32 threads per query row, float4 each.
__global__ __launch_bounds__(256) void reduce_gather(
    const float* __restrict__ feature, const float* __restrict__ bestd,
    const int* __restrict__ besti, float4* __restrict__ out) {
  const int t = blockIdx.x * 256 + threadIdx.x;
  const int q = t >> 5;
  const int j = t & 31;

  float bd = bestd[q];
  int bi = besti[q];
  #pragma unroll
  for (int s = 1; s < CSPLIT; ++s) {
    const float d = bestd[s * NQ + q];
    const int i2 = besti[s * NQ + q];
    if (d < bd) { bd = d; bi = i2; }
  }
  const float4* frow = (const float4*)(feature + (size_t)bi * CFEAT);
  out[(size_t)q * (CFEAT / 4) + j] = frow[j];
}

extern "C" void kernel_launch(void* const* d_in, const int* in_sizes, int n_in,
                              void* d_out, int out_size, void* d_ws, size_t ws_size,
                              hipStream_t stream) {
  const float* coords  = (const float*)d_in[0];   // [8192, 3]
  const float* feature = (const float*)d_in[1];   // [8192, 128]
  const float* points  = (const float*)d_in[2];   // [32768, 3]
  float* out = (float*)d_out;                     // [32768, 128]

  float* bestd = (float*)d_ws;                    // [CSPLIT * NQ]
  int*   besti = (int*)((char*)d_ws + (size_t)CSPLIT * NQ * sizeof(float));

  dim3 grid1(NQ / QPB, CSPLIT);                   // (64, 16) = 1024 blocks
  argmin_part<<<grid1, BLK, 0, stream>>>(coords, points, bestd, besti);

  const int total = NQ * (CFEAT / 4);             // one thread per float4
  reduce_gather<<<total / 256, 256, 0, stream>>>(feature, bestd, besti,
                                                 (float4*)out);
}